// Round 8
// baseline (209.059 us; speedup 1.0000x reference)
//
#include <hip/hip_runtime.h>
#include <hip/hip_bf16.h>
#include <stdint.h>

typedef _Float16 f16;
typedef _Float16 f16x8 __attribute__((ext_vector_type(8)));
typedef float    f32x4 __attribute__((ext_vector_type(4)));
typedef unsigned short u16;
typedef unsigned int   u32;

#define S_LEN 1536
#define NDIM  1024
#define MROWS 3072

__device__ __forceinline__ u16 f2h(float f){           // fp32 -> f16 bits (RNE)
  _Float16 h = (_Float16)f;
  return __builtin_bit_cast(u16, h);
}

// async global->LDS, 16B per lane, LDS dest = wave-uniform base + lane*16
#define GLDS16(g, l) __builtin_amdgcn_global_load_lds( \
    (const __attribute__((address_space(1))) u32*)(const void*)(g), \
    (__attribute__((address_space(3))) u32*)(void*)(l), 16, 0, 0)

// ---------------------------------------------------------------------------
// Cast fp32 -> f16 bits, 8 elems/thread.
// ---------------------------------------------------------------------------
__global__ __launch_bounds__(256) void cast_f32_f16(
    const float* __restrict__ in, u16* __restrict__ out)
{
  const int i = blockIdx.x * 256 + threadIdx.x;
  const float4* p = (const float4*)in;
  float4 a = p[i*2], b = p[i*2+1];
  alignas(16) u16 tmp[8];
  tmp[0]=f2h(a.x); tmp[1]=f2h(a.y); tmp[2]=f2h(a.z); tmp[3]=f2h(a.w);
  tmp[4]=f2h(b.x); tmp[5]=f2h(b.y); tmp[6]=f2h(b.z); tmp[7]=f2h(b.w);
  *(uint4*)(out + (size_t)i*8) = *(const uint4*)tmp;
}

// ---------------------------------------------------------------------------
// Transpose 4 fp32 [1024][1024] matrices -> f16 WT[n][k].
// ---------------------------------------------------------------------------
__global__ __launch_bounds__(256) void transpose4(
    const float* __restrict__ w0, const float* __restrict__ w1,
    const float* __restrict__ w2, const float* __restrict__ w3,
    u16* __restrict__ out)
{
  const float* W = (blockIdx.z==0)?w0:(blockIdx.z==1)?w1:(blockIdx.z==2)?w2:w3;
  u16* O = out + (size_t)blockIdx.z * (1024u*1024u);
  __shared__ __align__(16) u16 T[64*72];
  const int t = threadIdx.x;
  const int r0 = blockIdx.y*64, c0 = blockIdx.x*64;
  #pragma unroll
  for (int i=0;i<2;i++){
    int v = t + i*256;
    int row = v >> 3, col = (v & 7) * 8;
    const float* src = W + (size_t)(r0+row)*NDIM + c0 + col;
    float4 a = *(const float4*)src;
    float4 b = *(const float4*)(src + 4);
    alignas(16) u16 tmp[8];
    tmp[0]=f2h(a.x); tmp[1]=f2h(a.y); tmp[2]=f2h(a.z); tmp[3]=f2h(a.w);
    tmp[4]=f2h(b.x); tmp[5]=f2h(b.y); tmp[6]=f2h(b.z); tmp[7]=f2h(b.w);
    *(uint4*)(T + row*72 + col) = *(const uint4*)tmp;
  }
  __syncthreads();
  #pragma unroll
  for (int i=0;i<2;i++){
    int v = t + i*256;
    int cc = v >> 3, rr = (v & 7) * 8;
    alignas(16) u16 tmp[8];
    #pragma unroll
    for (int j=0;j<8;j++) tmp[j] = T[(rr+j)*72 + cc];
    *(uint4*)(O + (size_t)(c0+cc)*NDIM + r0 + rr) = *(const uint4*)tmp;
  }
}

// ---------------------------------------------------------------------------
// C[M,1024] = A[M,1024] @ B + bias.  A f16, BT f16 (transposed).
// R8 structure: A staged via GLDS16 into LDS (barrier-gated); B-fragments
// loaded DIRECTLY global->VGPR (16 B/lane dwordx4; W^T is 2 MB, L2/L3-hot).
// Rationale (R7 post-mortem): the barrier-gated LDS staging path saturates
// ~20 B/cyc/CU — duration tracks staged bytes, not resident blocks. B-direct
// halves barrier-gated bytes (590->295 MB for QKV) and rides the same
// barrier drain as A instead of serializing behind it. LDS = As only
// (TM=128: 16 KiB; TM=64: 8 KiB). Tile TM x 64, BK=64 (two [.][32]
// subtiles, verified unpadded GLDS16 layout), 2 barriers/iter.
// QKV: TM=128, grid 16x24x3 = 1152 (4.5/CU). Out-proj: TM=64, grid 768.
// ---------------------------------------------------------------------------
#define SUBK 32

template<int TM>
__global__ __launch_bounds__(256) void gemm_bias_rope(
    const u16* __restrict__ A,     // [M][1024] f16
    const u16* __restrict__ BT,    // nmats x [1024][1024] f16 (transposed)
    const float* __restrict__ b0, const float* __restrict__ b1,
    const float* __restrict__ b2,
    u16*   __restrict__ Ch,        // f16 out (nmats slabs) or null
    float* __restrict__ Cf,        // fp32 out (z==0 only) or null
    const int* __restrict__ pos,
    int M, int rope_mats, int f32_out)
{
  constexpr int MI   = TM / 32;        // acc row-tiles per wave (4 or 2)
  constexpr int AW   = TM / 4;         // A rows staged per wave (32 or 16)

  __shared__ __align__(16) u16 As[TM*64];   // 2 subtiles of [TM][32]

  const int t    = threadIdx.x;
  const int lane = t & 63;
  const int wave = t >> 6;        // 0..3
  const int z    = blockIdx.z;
  const int m0   = blockIdx.y * TM;
  const int n0   = blockIdx.x * 64;
  const u16* Bm  = BT + (size_t)z * (1024u*1024u);
  u16*       Cm  = Ch ? (Ch + (size_t)z * ((size_t)M * NDIM)) : (u16*)0;
  const float* bias = (z==0) ? b0 : ((z==1) ? b1 : b2);

  const int wm   = (wave >> 1) * (TM/2);   // {0,TM/2}
  const int wn   = (wave & 1) * 32;        // {0,32}
  const int l15  = lane & 15;
  const int quad = lane >> 4;

  // staging lane map: one GLDS16 = 16 rows x 32 cols (64 lanes x 16B)
  const int lrow = lane >> 2;
  const int lcol = (lane & 3) * 8;
  const u16* gA = A + (size_t)(m0 + wave*AW + lrow)*NDIM + lcol;
  u16* lA = As + (wave*AW)*SUBK;   // wave-uniform LDS base (subtile 0)

  // per-lane B-fragment base: row n0+wn+{0,16}+l15, k-offset quad*8
  const u16* gBf = Bm + (size_t)(n0 + wn + l15)*NDIM + quad*8;

  f32x4 acc[MI][2];
  #pragma unroll
  for (int i=0;i<MI;i++)
    #pragma unroll
    for (int j=0;j<2;j++)
      acc[i][j] = (f32x4){0.f,0.f,0.f,0.f};

  for (int k0 = 0; k0 < 1024; k0 += 64) {
    // B-frags direct global->VGPR (issued before the barrier so their
    // latency overlaps the A GLDS16 drain)
    f16x8 bfr[2][2];
    #pragma unroll
    for (int kb=0;kb<2;kb++)
      #pragma unroll
      for (int j=0;j<2;j++)
        bfr[kb][j] = *(const f16x8*)(gBf + (size_t)(j*16)*NDIM + k0 + kb*SUBK);
    // A -> LDS (async, wave-uniform base + lane*16)
    #pragma unroll
    for (int kb=0;kb<2;kb++){
      const u16* ga = gA + k0 + kb*SUBK;
      u16* lak = lA + kb*(TM*SUBK);
      GLDS16(ga, lak);
      if (TM == 128) GLDS16(ga + 16*NDIM, lak + 16*SUBK);
    }
    __syncthreads();                       // vmcnt(0) drain + barrier
    #pragma unroll
    for (int kb=0;kb<2;kb++){
      f16x8 af[MI];
      #pragma unroll
      for (int i=0;i<MI;i++)
        af[i] = *(const f16x8*)(As + kb*(TM*SUBK) + (wm + i*16 + l15)*SUBK + quad*8);
      #pragma unroll
      for (int i=0;i<MI;i++)
        #pragma unroll
        for (int j=0;j<2;j++)
          acc[i][j] = __builtin_amdgcn_mfma_f32_16x16x32_f16(
                          af[i], bfr[kb][j], acc[i][j], 0, 0, 0);
    }
    __syncthreads();
  }

  // epilogue: bias (+ RoPE on cols 0..63 = head 0, tile n0==0) and store
  const bool rope_tile = (z < rope_mats) && (n0 == 0);
  #pragma unroll
  for (int i=0;i<MI;i++){
    const int rbase = m0 + wm + i*16 + quad*4;
    #pragma unroll
    for (int j=0;j<2;j++){
      const int c  = n0 + wn + j*16 + l15;
      const float bv = bias[c];
      f32x4 v4 = acc[i][j];
      #pragma unroll
      for (int r=0;r<4;r++) v4[r] += bv;
      if (rope_tile) {
        const int   ii  = c >> 1;
        const float inv = powf(10000.0f, -(float)ii * (1.0f/32.0f));
        const float sgn = (c & 1) ? 1.0f : -1.0f;
        #pragma unroll
        for (int r=0;r<4;r++){
          float val     = v4[r];
          float partner = __shfl_xor(val, 1, 64);   // col c^1 lives in lane^1
          int   srow    = (rbase + r) % S_LEN;
          float ang     = (float)pos[srow] * inv;
          float sv, cv;
          sincosf(ang, &sv, &cv);
          v4[r] = val * cv + sgn * partner * sv;
        }
      }
      if (f32_out) {
        #pragma unroll
        for (int r=0;r<4;r++)
          Cf[(size_t)(rbase + r)*NDIM + c] = v4[r];
      } else {
        #pragma unroll
        for (int r=0;r<4;r++)
          Cm[(size_t)(rbase + r)*NDIM + c] = f2h(v4[r]);
      }
    }
  }
}

// ---------------------------------------------------------------------------
// Block-banded attention, MFMA version (unchanged — revisit when it tops
// the profile).
// ---------------------------------------------------------------------------
__global__ __launch_bounds__(256) void attn_kernel(
    const u16* __restrict__ q, const u16* __restrict__ k,
    const u16* __restrict__ v, u16* __restrict__ o)
{
  const int qb = blockIdx.x;   // 0..63
  const int h  = blockIdx.y;   // 0..15
  const int b  = blockIdx.z;   // 0..1
  const int t  = threadIdx.x;
  const int lane = t & 63;
  const int wave = t >> 6;     // 0..3
  const int l15  = lane & 15;
  const int quad = lane >> 4;

  const int ks_ = (qb == 0) ? 0 : (qb - 1) * 24;
  const int ke_ = min(S_LEN, (qb + 2) * 24);
  const int kn  = ke_ - ks_;             // 48 or 72

  __shared__ __align__(16) u16   Qs[32*72];
  __shared__ __align__(16) u16   Ks[80*72];
  __shared__ __align__(16) u16   Vt[64*104];
  __shared__ __align__(16) float Ss[32*80];
  __shared__ __align__(16) u16   Ps[32*104];

  const size_t qrow0 = (size_t)b*S_LEN + qb*24;
  const size_t krow0 = (size_t)b*S_LEN + ks_;
  const int hoff = h * 64;

  if (t < 192) {
    int row = t >> 3, col = (t & 7) * 8;
    *(uint4*)(Qs + row*72 + col) = *(const uint4*)(q + (qrow0+row)*NDIM + hoff + col);
  }
  for (int e = t; e < kn*8; e += 256) {
    int row = e >> 3, col = (e & 7) * 8;
    *(uint4*)(Ks + row*72 + col) = *(const uint4*)(k + (krow0+row)*NDIM + hoff + col);
    uint4 vv = *(const uint4*)(v + (krow0+row)*NDIM + hoff + col);
    const u16* pu = (const u16*)&vv;
    #pragma unroll
    for (int j=0;j<8;j++) Vt[(col+j)*104 + row] = pu[j];
  }
  for (int e = t; e < 64*48; e += 256) {
    int d = e / 48, c = 48 + (e - (e/48)*48);
    if (c >= kn) Vt[d*104 + c] = 0;
  }
  __syncthreads();

  const int ntn = (kn + 15) >> 4;
  for (int id = wave; id < 2*ntn; id += 4) {
    int mt = id / ntn, nt = id - (id/ntn)*ntn;
    f32x4 acc = (f32x4){0.f,0.f,0.f,0.f};
    #pragma unroll
    for (int ks2 = 0; ks2 < 2; ks2++) {
      f16x8 a = *(const f16x8*)(Qs + (mt*16 + l15)*72 + ks2*32 + quad*8);
      f16x8 bb= *(const f16x8*)(Ks + (nt*16 + l15)*72 + ks2*32 + quad*8);
      acc = __builtin_amdgcn_mfma_f32_16x16x32_f16(a, bb, acc, 0, 0, 0);
    }
    #pragma unroll
    for (int r=0;r<4;r++)
      Ss[(mt*16 + quad*4 + r)*80 + nt*16 + l15] = acc[r] * 0.125f;
  }
  __syncthreads();

  #pragma unroll
  for (int i=0;i<6;i++){
    int row = wave*6 + i;
    float v0 = (lane      < kn) ? Ss[row*80 + lane]      : -1e30f;
    float v1 = (lane + 64 < kn) ? Ss[row*80 + 64 + lane] : -1e30f;
    float m = fmaxf(v0, v1);
    #pragma unroll
    for (int off=32; off; off>>=1) m = fmaxf(m, __shfl_xor(m, off, 64));
    float p0 = __expf(v0 - m);
    float p1 = __expf(v1 - m);
    float s = p0 + p1;
    #pragma unroll
    for (int off=32; off; off>>=1) s += __shfl_xor(s, off, 64);
    float inv = 1.0f / s;
    Ps[row*104 + lane] = f2h(p0 * inv);
    if (lane < 32) Ps[row*104 + 64 + lane] = f2h(p1 * inv);
  }
  __syncthreads();

  const int kceil = (kn + 31) >> 5;
  #pragma unroll
  for (int id2 = 0; id2 < 2; id2++){
    int id = wave*2 + id2;
    int mt = id >> 2, nt = id & 3;
    f32x4 acc = (f32x4){0.f,0.f,0.f,0.f};
    for (int ks2 = 0; ks2 < kceil; ks2++) {
      f16x8 a = *(const f16x8*)(Ps + (mt*16 + l15)*104 + ks2*32 + quad*8);
      f16x8 bb= *(const f16x8*)(Vt + (nt*16 + l15)*104 + ks2*32 + quad*8);
      acc = __builtin_amdgcn_mfma_f32_16x16x32_f16(a, bb, acc, 0, 0, 0);
    }
    #pragma unroll
    for (int r=0;r<4;r++){
      int row = mt*16 + quad*4 + r;
      if (row < 24)
        o[(qrow0 + row)*NDIM + hoff + nt*16 + l15] = f2h(acc[r]);
    }
  }
}

// ---------------------------------------------------------------------------
extern "C" void kernel_launch(void* const* d_in, const int* in_sizes, int n_in,
                              void* d_out, int out_size, void* d_ws, size_t ws_size,
                              hipStream_t stream)
{
  const float* x   = (const float*)d_in[0];
  const float* Wq  = (const float*)d_in[1];
  const float* bq  = (const float*)d_in[2];
  const float* Wk  = (const float*)d_in[3];
  const float* bk  = (const float*)d_in[4];
  const float* Wv  = (const float*)d_in[5];
  const float* bv  = (const float*)d_in[6];
  const float* Wo  = (const float*)d_in[7];
  const float* bo  = (const float*)d_in[8];
  const int*   pos = (const int*)d_in[9];

  u16* ws   = (u16*)d_ws;
  u16* WT   = ws;                               // 4 * 1M elems (8 MiB)
  u16* xb   = WT + 4u*1024u*1024u;              // 3072*1024 (6 MiB)
  u16* qkv  = xb + (size_t)MROWS*NDIM;          // 3 * 3072*1024 (18 MiB)
  u16* attn = WT;                               // overlay Wq/Wk/Wv^T slabs (6 MiB)
  float* outf = (float*)d_out;                  // fp32 [3072][1024]

  cast_f32_f16<<<dim3(MROWS*NDIM/(256*8)), 256, 0, stream>>>(x, xb);
  transpose4<<<dim3(16,16,4), 256, 0, stream>>>(Wq, Wk, Wv, Wo, WT);
  gemm_bias_rope<128><<<dim3(16,24,3), 256, 0, stream>>>(
      xb, WT, bq, bk, bv, qkv, nullptr, pos, MROWS, /*rope_mats=*/2, /*f32_out=*/0);
  attn_kernel<<<dim3(64,16,2), 256, 0, stream>>>(
      qkv, qkv + (size_t)MROWS*NDIM, qkv + 2u*(size_t)MROWS*NDIM, attn);
  gemm_bias_rope<64><<<dim3(16,48,1), 256, 0, stream>>>(
      attn, WT + 3u*1024u*1024u, bo, bo, bo, nullptr, outf, pos, MROWS,
      /*rope_mats=*/0, /*f32_out=*/1);
}

// Round 9
// 177.844 us; speedup vs baseline: 1.1755x; 1.1755x over previous
//
#include <hip/hip_runtime.h>
#include <hip/hip_bf16.h>
#include <stdint.h>

typedef _Float16 f16;
typedef _Float16 f16x8 __attribute__((ext_vector_type(8)));
typedef float    f32x4 __attribute__((ext_vector_type(4)));
typedef unsigned short u16;
typedef unsigned int   u32;

#define S_LEN 1536
#define NDIM  1024
#define MROWS 3072

__device__ __forceinline__ u16 f2h(float f){           // fp32 -> f16 bits (RNE)
  _Float16 h = (_Float16)f;
  return __builtin_bit_cast(u16, h);
}

// async global->LDS, 16B per lane, LDS dest = wave-uniform base + lane*16
#define GLDS16(g, l) __builtin_amdgcn_global_load_lds( \
    (const __attribute__((address_space(1))) u32*)(const void*)(g), \
    (__attribute__((address_space(3))) u32*)(void*)(l), 16, 0, 0)

// ---------------------------------------------------------------------------
// Cast fp32 -> f16 bits, 8 elems/thread.
// ---------------------------------------------------------------------------
__global__ __launch_bounds__(256) void cast_f32_f16(
    const float* __restrict__ in, u16* __restrict__ out)
{
  const int i = blockIdx.x * 256 + threadIdx.x;
  const float4* p = (const float4*)in;
  float4 a = p[i*2], b = p[i*2+1];
  alignas(16) u16 tmp[8];
  tmp[0]=f2h(a.x); tmp[1]=f2h(a.y); tmp[2]=f2h(a.z); tmp[3]=f2h(a.w);
  tmp[4]=f2h(b.x); tmp[5]=f2h(b.y); tmp[6]=f2h(b.z); tmp[7]=f2h(b.w);
  *(uint4*)(out + (size_t)i*8) = *(const uint4*)tmp;
}

// ---------------------------------------------------------------------------
// Transpose 4 fp32 [1024][1024] matrices -> f16 WT[n][k].
// ---------------------------------------------------------------------------
__global__ __launch_bounds__(256) void transpose4(
    const float* __restrict__ w0, const float* __restrict__ w1,
    const float* __restrict__ w2, const float* __restrict__ w3,
    u16* __restrict__ out)
{
  const float* W = (blockIdx.z==0)?w0:(blockIdx.z==1)?w1:(blockIdx.z==2)?w2:w3;
  u16* O = out + (size_t)blockIdx.z * (1024u*1024u);
  __shared__ __align__(16) u16 T[64*72];
  const int t = threadIdx.x;
  const int r0 = blockIdx.y*64, c0 = blockIdx.x*64;
  #pragma unroll
  for (int i=0;i<2;i++){
    int v = t + i*256;
    int row = v >> 3, col = (v & 7) * 8;
    const float* src = W + (size_t)(r0+row)*NDIM + c0 + col;
    float4 a = *(const float4*)src;
    float4 b = *(const float4*)(src + 4);
    alignas(16) u16 tmp[8];
    tmp[0]=f2h(a.x); tmp[1]=f2h(a.y); tmp[2]=f2h(a.z); tmp[3]=f2h(a.w);
    tmp[4]=f2h(b.x); tmp[5]=f2h(b.y); tmp[6]=f2h(b.z); tmp[7]=f2h(b.w);
    *(uint4*)(T + row*72 + col) = *(const uint4*)tmp;
  }
  __syncthreads();
  #pragma unroll
  for (int i=0;i<2;i++){
    int v = t + i*256;
    int cc = v >> 3, rr = (v & 7) * 8;
    alignas(16) u16 tmp[8];
    #pragma unroll
    for (int j=0;j<8;j++) tmp[j] = T[(rr+j)*72 + cc];
    *(uint4*)(O + (size_t)(c0+cc)*NDIM + r0 + rr) = *(const uint4*)tmp;
  }
}

// ---------------------------------------------------------------------------
// C[M,1024] = A[M,1024] @ B + bias.  A f16, BT f16 (transposed).
// R9 structure: R7 (A+B staged via GLDS16, verified unpadded layout,
// 2 barriers/iter) but BK=128 (4 [.][32] subtiles): halves the number of
// barrier-drain events (16 -> 8 K-iters) while LDS stays 32 KiB -> 5
// resident blocks/CU, above the ~4.5 blk/CU overlap-saturation knee
// measured across R3-R7 (this dodges the m132/R5 occupancy trap).
// History: B-direct VGPR (R8) regressed — scattered 2KB-stride gather +
// 2x B traffic. dbuf (R5) regressed — 48 KiB -> 3 blk/CU.
// TM=64: 4 waves as 2x2 (32x32 quadrant, acc 2x2). Both GEMMs use TM=64.
// ---------------------------------------------------------------------------
#define SUBK 32

template<int TM>
__global__ __launch_bounds__(256) void gemm_bias_rope(
    const u16* __restrict__ A,     // [M][1024] f16
    const u16* __restrict__ BT,    // nmats x [1024][1024] f16 (transposed)
    const float* __restrict__ b0, const float* __restrict__ b1,
    const float* __restrict__ b2,
    u16*   __restrict__ Ch,        // f16 out (nmats slabs) or null
    float* __restrict__ Cf,        // fp32 out (z==0 only) or null
    const int* __restrict__ pos,
    int M, int rope_mats, int f32_out)
{
  constexpr int TN   = 64;
  constexpr int MI   = TM / 32;        // acc row-tiles per wave (2 for TM=64)
  constexpr int AW   = TM / 4;         // A rows staged per wave (16)

  __shared__ __align__(16) u16 As[TM*128];  // 4 subtiles of [TM][32] (16 KiB)
  __shared__ __align__(16) u16 Bs[TN*128];  // 4 subtiles of [TN][32] (16 KiB)

  const int t    = threadIdx.x;
  const int lane = t & 63;
  const int wave = t >> 6;        // 0..3
  const int z    = blockIdx.z;
  const int m0   = blockIdx.y * TM;
  const int n0   = blockIdx.x * 64;
  const u16* Bm  = BT + (size_t)z * (1024u*1024u);
  u16*       Cm  = Ch ? (Ch + (size_t)z * ((size_t)M * NDIM)) : (u16*)0;
  const float* bias = (z==0) ? b0 : ((z==1) ? b1 : b2);

  const int wm   = (wave >> 1) * (TM/2);   // {0,TM/2}
  const int wn   = (wave & 1) * 32;        // {0,32}
  const int l15  = lane & 15;
  const int quad = lane >> 4;

  // staging lane map: one GLDS16 = 16 rows x 32 cols (64 lanes x 16B)
  const int lrow = lane >> 2;
  const int lcol = (lane & 3) * 8;
  const u16* gA = A  + (size_t)(m0 + wave*AW + lrow)*NDIM + lcol;
  const u16* gB = Bm + (size_t)(n0 + wave*16 + lrow)*NDIM + lcol;
  u16* lA = As + (wave*AW)*SUBK;   // wave-uniform LDS bases (subtile 0)
  u16* lB = Bs + (wave*16)*SUBK;

  f32x4 acc[MI][2];
  #pragma unroll
  for (int i=0;i<MI;i++)
    #pragma unroll
    for (int j=0;j<2;j++)
      acc[i][j] = (f32x4){0.f,0.f,0.f,0.f};

  for (int k0 = 0; k0 < 1024; k0 += 128) {
    #pragma unroll
    for (int kb=0;kb<4;kb++){
      const u16* ga = gA + k0 + kb*SUBK;
      u16* lak = lA + kb*(TM*SUBK);
      GLDS16(ga, lak);
      if (TM == 128) GLDS16(ga + 16*NDIM, lak + 16*SUBK);
      GLDS16(gB + k0 + kb*SUBK, lB + kb*(TN*SUBK));
    }
    __syncthreads();                       // vmcnt(0) drain + barrier
    #pragma unroll
    for (int kb=0;kb<4;kb++){
      f16x8 af[MI], bfr[2];
      #pragma unroll
      for (int i=0;i<MI;i++)
        af[i]  = *(const f16x8*)(As + kb*(TM*SUBK) + (wm + i*16 + l15)*SUBK + quad*8);
      #pragma unroll
      for (int j=0;j<2;j++)
        bfr[j] = *(const f16x8*)(Bs + kb*(TN*SUBK) + (wn + j*16 + l15)*SUBK + quad*8);
      #pragma unroll
      for (int i=0;i<MI;i++)
        #pragma unroll
        for (int j=0;j<2;j++)
          acc[i][j] = __builtin_amdgcn_mfma_f32_16x16x32_f16(
                          af[i], bfr[j], acc[i][j], 0, 0, 0);
    }
    __syncthreads();
  }

  // epilogue: bias (+ RoPE on cols 0..63 = head 0, tile n0==0) and store
  const bool rope_tile = (z < rope_mats) && (n0 == 0);
  #pragma unroll
  for (int i=0;i<MI;i++){
    const int rbase = m0 + wm + i*16 + quad*4;
    #pragma unroll
    for (int j=0;j<2;j++){
      const int c  = n0 + wn + j*16 + l15;
      const float bv = bias[c];
      f32x4 v4 = acc[i][j];
      #pragma unroll
      for (int r=0;r<4;r++) v4[r] += bv;
      if (rope_tile) {
        const int   ii  = c >> 1;
        const float inv = powf(10000.0f, -(float)ii * (1.0f/32.0f));
        const float sgn = (c & 1) ? 1.0f : -1.0f;
        #pragma unroll
        for (int r=0;r<4;r++){
          float val     = v4[r];
          float partner = __shfl_xor(val, 1, 64);   // col c^1 lives in lane^1
          int   srow    = (rbase + r) % S_LEN;
          float ang     = (float)pos[srow] * inv;
          float sv, cv;
          sincosf(ang, &sv, &cv);
          v4[r] = val * cv + sgn * partner * sv;
        }
      }
      if (f32_out) {
        #pragma unroll
        for (int r=0;r<4;r++)
          Cf[(size_t)(rbase + r)*NDIM + c] = v4[r];
      } else {
        #pragma unroll
        for (int r=0;r<4;r++)
          Cm[(size_t)(rbase + r)*NDIM + c] = f2h(v4[r]);
      }
    }
  }
}

// ---------------------------------------------------------------------------
// Block-banded attention, MFMA version (unchanged — revisit when it tops
// the profile).
// ---------------------------------------------------------------------------
__global__ __launch_bounds__(256) void attn_kernel(
    const u16* __restrict__ q, const u16* __restrict__ k,
    const u16* __restrict__ v, u16* __restrict__ o)
{
  const int qb = blockIdx.x;   // 0..63
  const int h  = blockIdx.y;   // 0..15
  const int b  = blockIdx.z;   // 0..1
  const int t  = threadIdx.x;
  const int lane = t & 63;
  const int wave = t >> 6;     // 0..3
  const int l15  = lane & 15;
  const int quad = lane >> 4;

  const int ks_ = (qb == 0) ? 0 : (qb - 1) * 24;
  const int ke_ = min(S_LEN, (qb + 2) * 24);
  const int kn  = ke_ - ks_;             // 48 or 72

  __shared__ __align__(16) u16   Qs[32*72];
  __shared__ __align__(16) u16   Ks[80*72];
  __shared__ __align__(16) u16   Vt[64*104];
  __shared__ __align__(16) float Ss[32*80];
  __shared__ __align__(16) u16   Ps[32*104];

  const size_t qrow0 = (size_t)b*S_LEN + qb*24;
  const size_t krow0 = (size_t)b*S_LEN + ks_;
  const int hoff = h * 64;

  if (t < 192) {
    int row = t >> 3, col = (t & 7) * 8;
    *(uint4*)(Qs + row*72 + col) = *(const uint4*)(q + (qrow0+row)*NDIM + hoff + col);
  }
  for (int e = t; e < kn*8; e += 256) {
    int row = e >> 3, col = (e & 7) * 8;
    *(uint4*)(Ks + row*72 + col) = *(const uint4*)(k + (krow0+row)*NDIM + hoff + col);
    uint4 vv = *(const uint4*)(v + (krow0+row)*NDIM + hoff + col);
    const u16* pu = (const u16*)&vv;
    #pragma unroll
    for (int j=0;j<8;j++) Vt[(col+j)*104 + row] = pu[j];
  }
  for (int e = t; e < 64*48; e += 256) {
    int d = e / 48, c = 48 + (e - (e/48)*48);
    if (c >= kn) Vt[d*104 + c] = 0;
  }
  __syncthreads();

  const int ntn = (kn + 15) >> 4;
  for (int id = wave; id < 2*ntn; id += 4) {
    int mt = id / ntn, nt = id - (id/ntn)*ntn;
    f32x4 acc = (f32x4){0.f,0.f,0.f,0.f};
    #pragma unroll
    for (int ks2 = 0; ks2 < 2; ks2++) {
      f16x8 a = *(const f16x8*)(Qs + (mt*16 + l15)*72 + ks2*32 + quad*8);
      f16x8 bb= *(const f16x8*)(Ks + (nt*16 + l15)*72 + ks2*32 + quad*8);
      acc = __builtin_amdgcn_mfma_f32_16x16x32_f16(a, bb, acc, 0, 0, 0);
    }
    #pragma unroll
    for (int r=0;r<4;r++)
      Ss[(mt*16 + quad*4 + r)*80 + nt*16 + l15] = acc[r] * 0.125f;
  }
  __syncthreads();

  #pragma unroll
  for (int i=0;i<6;i++){
    int row = wave*6 + i;
    float v0 = (lane      < kn) ? Ss[row*80 + lane]      : -1e30f;
    float v1 = (lane + 64 < kn) ? Ss[row*80 + 64 + lane] : -1e30f;
    float m = fmaxf(v0, v1);
    #pragma unroll
    for (int off=32; off; off>>=1) m = fmaxf(m, __shfl_xor(m, off, 64));
    float p0 = __expf(v0 - m);
    float p1 = __expf(v1 - m);
    float s = p0 + p1;
    #pragma unroll
    for (int off=32; off; off>>=1) s += __shfl_xor(s, off, 64);
    float inv = 1.0f / s;
    Ps[row*104 + lane] = f2h(p0 * inv);
    if (lane < 32) Ps[row*104 + 64 + lane] = f2h(p1 * inv);
  }
  __syncthreads();

  const int kceil = (kn + 31) >> 5;
  #pragma unroll
  for (int id2 = 0; id2 < 2; id2++){
    int id = wave*2 + id2;
    int mt = id >> 2, nt = id & 3;
    f32x4 acc = (f32x4){0.f,0.f,0.f,0.f};
    for (int ks2 = 0; ks2 < kceil; ks2++) {
      f16x8 a = *(const f16x8*)(Ps + (mt*16 + l15)*104 + ks2*32 + quad*8);
      f16x8 bb= *(const f16x8*)(Vt + (nt*16 + l15)*104 + ks2*32 + quad*8);
      acc = __builtin_amdgcn_mfma_f32_16x16x32_f16(a, bb, acc, 0, 0, 0);
    }
    #pragma unroll
    for (int r=0;r<4;r++){
      int row = mt*16 + quad*4 + r;
      if (row < 24)
        o[(qrow0 + row)*NDIM + hoff + nt*16 + l15] = f2h(acc[r]);
    }
  }
}

// ---------------------------------------------------------------------------
extern "C" void kernel_launch(void* const* d_in, const int* in_sizes, int n_in,
                              void* d_out, int out_size, void* d_ws, size_t ws_size,
                              hipStream_t stream)
{
  const float* x   = (const float*)d_in[0];
  const float* Wq  = (const float*)d_in[1];
  const float* bq  = (const float*)d_in[2];
  const float* Wk  = (const float*)d_in[3];
  const float* bk  = (const float*)d_in[4];
  const float* Wv  = (const float*)d_in[5];
  const float* bv  = (const float*)d_in[6];
  const float* Wo  = (const float*)d_in[7];
  const float* bo  = (const float*)d_in[8];
  const int*   pos = (const int*)d_in[9];

  u16* ws   = (u16*)d_ws;
  u16* WT   = ws;                               // 4 * 1M elems (8 MiB)
  u16* xb   = WT + 4u*1024u*1024u;              // 3072*1024 (6 MiB)
  u16* qkv  = xb + (size_t)MROWS*NDIM;          // 3 * 3072*1024 (18 MiB)
  u16* attn = WT;                               // overlay Wq/Wk/Wv^T slabs (6 MiB)
  float* outf = (float*)d_out;                  // fp32 [3072][1024]

  cast_f32_f16<<<dim3(MROWS*NDIM/(256*8)), 256, 0, stream>>>(x, xb);
  transpose4<<<dim3(16,16,4), 256, 0, stream>>>(Wq, Wk, Wv, Wo, WT);
  gemm_bias_rope<64><<<dim3(16,48,3), 256, 0, stream>>>(
      xb, WT, bq, bk, bv, qkv, nullptr, pos, MROWS, /*rope_mats=*/2, /*f32_out=*/0);
  attn_kernel<<<dim3(64,16,2), 256, 0, stream>>>(
      qkv, qkv + (size_t)MROWS*NDIM, qkv + 2u*(size_t)MROWS*NDIM, attn);
  gemm_bias_rope<64><<<dim3(16,48,1), 256, 0, stream>>>(
      attn, WT + 3u*1024u*1024u, bo, bo, bo, nullptr, outf, pos, MROWS,
      /*rope_mats=*/0, /*f32_out=*/1);
}

// Round 10
// 175.476 us; speedup vs baseline: 1.1914x; 1.0135x over previous
//
#include <hip/hip_runtime.h>
#include <hip/hip_bf16.h>
#include <stdint.h>

typedef _Float16 f16;
typedef _Float16 f16x8 __attribute__((ext_vector_type(8)));
typedef float    f32x4 __attribute__((ext_vector_type(4)));
typedef unsigned short u16;
typedef unsigned int   u32;

#define S_LEN 1536
#define NDIM  1024
#define MROWS 3072

__device__ __forceinline__ u16 f2h(float f){           // fp32 -> f16 bits (RNE)
  _Float16 h = (_Float16)f;
  return __builtin_bit_cast(u16, h);
}

// async global->LDS, 16B per lane, LDS dest = wave-uniform base + lane*16
#define GLDS16(g, l) __builtin_amdgcn_global_load_lds( \
    (const __attribute__((address_space(1))) u32*)(const void*)(g), \
    (__attribute__((address_space(3))) u32*)(void*)(l), 16, 0, 0)

// ---------------------------------------------------------------------------
// Fused prep: blocks [0,1024) transpose the 4 weight matrices fp32->f16
// WT[n][k]; blocks [1024, 2560) cast x fp32->f16. One launch instead of two
// (R9 accounting: ~70 us of the 174 total is inter-launch overhead across 5
// serialized launches).
// ---------------------------------------------------------------------------
__global__ __launch_bounds__(256) void prep_kernel(
    const float* __restrict__ x,
    const float* __restrict__ w0, const float* __restrict__ w1,
    const float* __restrict__ w2, const float* __restrict__ w3,
    u16* __restrict__ wt_out, u16* __restrict__ xb_out)
{
  const int bid = blockIdx.x;
  const int t = threadIdx.x;
  if (bid >= 1024) {                       // ---- cast branch ----
    const int i = (bid - 1024) * 256 + t;  // elems [8i, 8i+8)
    const float4* p = (const float4*)x;
    float4 a = p[i*2], b = p[i*2+1];
    alignas(16) u16 tmp[8];
    tmp[0]=f2h(a.x); tmp[1]=f2h(a.y); tmp[2]=f2h(a.z); tmp[3]=f2h(a.w);
    tmp[4]=f2h(b.x); tmp[5]=f2h(b.y); tmp[6]=f2h(b.z); tmp[7]=f2h(b.w);
    *(uint4*)(xb_out + (size_t)i*8) = *(const uint4*)tmp;
    return;
  }
  // ---- transpose branch ----
  const int bx = bid & 15, by = (bid >> 4) & 15, bz = bid >> 8;
  const float* W = (bz==0)?w0:(bz==1)?w1:(bz==2)?w2:w3;
  u16* O = wt_out + (size_t)bz * (1024u*1024u);
  __shared__ __align__(16) u16 T[64*72];
  const int r0 = by*64, c0 = bx*64;
  #pragma unroll
  for (int i=0;i<2;i++){
    int v = t + i*256;
    int row = v >> 3, col = (v & 7) * 8;
    const float* src = W + (size_t)(r0+row)*NDIM + c0 + col;
    float4 a = *(const float4*)src;
    float4 b = *(const float4*)(src + 4);
    alignas(16) u16 tmp[8];
    tmp[0]=f2h(a.x); tmp[1]=f2h(a.y); tmp[2]=f2h(a.z); tmp[3]=f2h(a.w);
    tmp[4]=f2h(b.x); tmp[5]=f2h(b.y); tmp[6]=f2h(b.z); tmp[7]=f2h(b.w);
    *(uint4*)(T + row*72 + col) = *(const uint4*)tmp;
  }
  __syncthreads();
  #pragma unroll
  for (int i=0;i<2;i++){
    int v = t + i*256;
    int cc = v >> 3, rr = (v & 7) * 8;
    alignas(16) u16 tmp[8];
    #pragma unroll
    for (int j=0;j<8;j++) tmp[j] = T[(rr+j)*72 + cc];
    *(uint4*)(O + (size_t)(c0+cc)*NDIM + r0 + rr) = *(const uint4*)tmp;
  }
}

// ---------------------------------------------------------------------------
// C[M,1024] = A[M,1024] @ B + bias.  A f16, BT f16 (transposed).
// Proven R7/R4 single-buffer structure: tile TM x TN, BK=64 as two [.][32]
// subtiles (verified unpadded GLDS16 lane-contiguous layout), 2 barriers
// per K-iter. Config history: this structure is pinned at ~47-50 us for QKV
// once >=4.5 blk/CU (R4/R7/R9); dbuf (R5), B-direct (R8), BK=128 (R9) all
// neutral-or-worse. QKV: TM=64,TN=64, grid 16x48x3 (9 blk/CU, 48.5 us).
// Out-proj: TM=64,TN=32, grid 32x48 (6 blk/CU) — the out-proj was the one
// GEMM still below the ~4.5 blk/CU latency knee (was 3 blk/CU at TN=64).
// ---------------------------------------------------------------------------
#define SUBK 32

template<int TM, int TN>
__global__ __launch_bounds__(256) void gemm_bias_rope(
    const u16* __restrict__ A,     // [M][1024] f16
    const u16* __restrict__ BT,    // nmats x [1024][1024] f16 (transposed)
    const float* __restrict__ b0, const float* __restrict__ b1,
    const float* __restrict__ b2,
    u16*   __restrict__ Ch,        // f16 out (nmats slabs) or null
    float* __restrict__ Cf,        // fp32 out (z==0 only) or null
    const int* __restrict__ pos,
    int M, int rope_mats, int f32_out)
{
  constexpr int MI   = TM / 32;        // acc row-tiles per wave
  constexpr int NI   = TN / 32;        // acc col-tiles per wave
  constexpr int AW   = TM / 4;         // A rows staged per wave

  __shared__ __align__(16) u16 As[TM*64];   // 2 subtiles of [TM][32]
  __shared__ __align__(16) u16 Bs[TN*64];

  const int t    = threadIdx.x;
  const int lane = t & 63;
  const int wave = t >> 6;        // 0..3
  const int z    = blockIdx.z;
  const int m0   = blockIdx.y * TM;
  const int n0   = blockIdx.x * TN;
  const u16* Bm  = BT + (size_t)z * (1024u*1024u);
  u16*       Cm  = Ch ? (Ch + (size_t)z * ((size_t)M * NDIM)) : (u16*)0;
  const float* bias = (z==0) ? b0 : ((z==1) ? b1 : b2);

  const int wm   = (wave >> 1) * (TM/2);
  const int wn   = (wave & 1) * (TN/2);
  const int l15  = lane & 15;
  const int quad = lane >> 4;

  // staging lane map: one GLDS16 = 16 rows x 32 cols (64 lanes x 16B)
  const int lrow = lane >> 2;
  const int lcol = (lane & 3) * 8;
  const u16* gA = A  + (size_t)(m0 + wave*AW + lrow)*NDIM + lcol;
  const u16* gB = Bm + (size_t)(n0 + (wave*16 % TN) + lrow)*NDIM + lcol;
  u16* lA = As + (wave*AW)*SUBK;   // wave-uniform LDS bases (subtile 0)
  u16* lB = Bs + ((wave*16 % TN))*SUBK;
  const bool bstage = (TN == 64) || (wave < TN/16);

  f32x4 acc[MI][NI];
  #pragma unroll
  for (int i=0;i<MI;i++)
    #pragma unroll
    for (int j=0;j<NI;j++)
      acc[i][j] = (f32x4){0.f,0.f,0.f,0.f};

  for (int k0 = 0; k0 < 1024; k0 += 64) {
    #pragma unroll
    for (int kb=0;kb<2;kb++){
      const u16* ga = gA + k0 + kb*SUBK;
      u16* lak = lA + kb*(TM*SUBK);
      GLDS16(ga, lak);
      if (TM == 128) GLDS16(ga + 16*NDIM, lak + 16*SUBK);
      if (bstage) GLDS16(gB + k0 + kb*SUBK, lB + kb*(TN*SUBK));
    }
    __syncthreads();                       // vmcnt(0) drain + barrier
    #pragma unroll
    for (int kb=0;kb<2;kb++){
      f16x8 af[MI], bfr[NI];
      #pragma unroll
      for (int i=0;i<MI;i++)
        af[i]  = *(const f16x8*)(As + kb*(TM*SUBK) + (wm + i*16 + l15)*SUBK + quad*8);
      #pragma unroll
      for (int j=0;j<NI;j++)
        bfr[j] = *(const f16x8*)(Bs + kb*(TN*SUBK) + (wn + j*16 + l15)*SUBK + quad*8);
      #pragma unroll
      for (int i=0;i<MI;i++)
        #pragma unroll
        for (int j=0;j<NI;j++)
          acc[i][j] = __builtin_amdgcn_mfma_f32_16x16x32_f16(
                          af[i], bfr[j], acc[i][j], 0, 0, 0);
    }
    __syncthreads();
  }

  // epilogue: bias (+ RoPE on cols 0..63 = head 0, tile n0==0) and store
  const bool rope_tile = (z < rope_mats) && (n0 == 0);
  #pragma unroll
  for (int i=0;i<MI;i++){
    const int rbase = m0 + wm + i*16 + quad*4;
    #pragma unroll
    for (int j=0;j<NI;j++){
      const int c  = n0 + wn + j*16 + l15;
      const float bv = bias[c];
      f32x4 v4 = acc[i][j];
      #pragma unroll
      for (int r=0;r<4;r++) v4[r] += bv;
      if (rope_tile) {
        const int   ii  = c >> 1;
        const float inv = powf(10000.0f, -(float)ii * (1.0f/32.0f));
        const float sgn = (c & 1) ? 1.0f : -1.0f;
        #pragma unroll
        for (int r=0;r<4;r++){
          float val     = v4[r];
          float partner = __shfl_xor(val, 1, 64);   // col c^1 lives in lane^1
          int   srow    = (rbase + r) % S_LEN;
          float ang     = (float)pos[srow] * inv;
          float sv, cv;
          sincosf(ang, &sv, &cv);
          v4[r] = val * cv + sgn * partner * sv;
        }
      }
      if (f32_out) {
        #pragma unroll
        for (int r=0;r<4;r++)
          Cf[(size_t)(rbase + r)*NDIM + c] = v4[r];
      } else {
        #pragma unroll
        for (int r=0;r<4;r++)
          Cm[(size_t)(rbase + r)*NDIM + c] = f2h(v4[r]);
      }
    }
  }
}

// ---------------------------------------------------------------------------
// Block-banded attention, MFMA version (unchanged — revisit if the R10
// launch-overhead theory fails).
// ---------------------------------------------------------------------------
__global__ __launch_bounds__(256) void attn_kernel(
    const u16* __restrict__ q, const u16* __restrict__ k,
    const u16* __restrict__ v, u16* __restrict__ o)
{
  const int qb = blockIdx.x;   // 0..63
  const int h  = blockIdx.y;   // 0..15
  const int b  = blockIdx.z;   // 0..1
  const int t  = threadIdx.x;
  const int lane = t & 63;
  const int wave = t >> 6;     // 0..3
  const int l15  = lane & 15;
  const int quad = lane >> 4;

  const int ks_ = (qb == 0) ? 0 : (qb - 1) * 24;
  const int ke_ = min(S_LEN, (qb + 2) * 24);
  const int kn  = ke_ - ks_;             // 48 or 72

  __shared__ __align__(16) u16   Qs[32*72];
  __shared__ __align__(16) u16   Ks[80*72];
  __shared__ __align__(16) u16   Vt[64*104];
  __shared__ __align__(16) float Ss[32*80];
  __shared__ __align__(16) u16   Ps[32*104];

  const size_t qrow0 = (size_t)b*S_LEN + qb*24;
  const size_t krow0 = (size_t)b*S_LEN + ks_;
  const int hoff = h * 64;

  if (t < 192) {
    int row = t >> 3, col = (t & 7) * 8;
    *(uint4*)(Qs + row*72 + col) = *(const uint4*)(q + (qrow0+row)*NDIM + hoff + col);
  }
  for (int e = t; e < kn*8; e += 256) {
    int row = e >> 3, col = (e & 7) * 8;
    *(uint4*)(Ks + row*72 + col) = *(const uint4*)(k + (krow0+row)*NDIM + hoff + col);
    uint4 vv = *(const uint4*)(v + (krow0+row)*NDIM + hoff + col);
    const u16* pu = (const u16*)&vv;
    #pragma unroll
    for (int j=0;j<8;j++) Vt[(col+j)*104 + row] = pu[j];
  }
  for (int e = t; e < 64*48; e += 256) {
    int d = e / 48, c = 48 + (e - (e/48)*48);
    if (c >= kn) Vt[d*104 + c] = 0;
  }
  __syncthreads();

  const int ntn = (kn + 15) >> 4;
  for (int id = wave; id < 2*ntn; id += 4) {
    int mt = id / ntn, nt = id - (id/ntn)*ntn;
    f32x4 acc = (f32x4){0.f,0.f,0.f,0.f};
    #pragma unroll
    for (int ks2 = 0; ks2 < 2; ks2++) {
      f16x8 a = *(const f16x8*)(Qs + (mt*16 + l15)*72 + ks2*32 + quad*8);
      f16x8 bb= *(const f16x8*)(Ks + (nt*16 + l15)*72 + ks2*32 + quad*8);
      acc = __builtin_amdgcn_mfma_f32_16x16x32_f16(a, bb, acc, 0, 0, 0);
    }
    #pragma unroll
    for (int r=0;r<4;r++)
      Ss[(mt*16 + quad*4 + r)*80 + nt*16 + l15] = acc[r] * 0.125f;
  }
  __syncthreads();

  #pragma unroll
  for (int i=0;i<6;i++){
    int row = wave*6 + i;
    float v0 = (lane      < kn) ? Ss[row*80 + lane]      : -1e30f;
    float v1 = (lane + 64 < kn) ? Ss[row*80 + 64 + lane] : -1e30f;
    float m = fmaxf(v0, v1);
    #pragma unroll
    for (int off=32; off; off>>=1) m = fmaxf(m, __shfl_xor(m, off, 64));
    float p0 = __expf(v0 - m);
    float p1 = __expf(v1 - m);
    float s = p0 + p1;
    #pragma unroll
    for (int off=32; off; off>>=1) s += __shfl_xor(s, off, 64);
    float inv = 1.0f / s;
    Ps[row*104 + lane] = f2h(p0 * inv);
    if (lane < 32) Ps[row*104 + 64 + lane] = f2h(p1 * inv);
  }
  __syncthreads();

  const int kceil = (kn + 31) >> 5;
  #pragma unroll
  for (int id2 = 0; id2 < 2; id2++){
    int id = wave*2 + id2;
    int mt = id >> 2, nt = id & 3;
    f32x4 acc = (f32x4){0.f,0.f,0.f,0.f};
    for (int ks2 = 0; ks2 < kceil; ks2++) {
      f16x8 a = *(const f16x8*)(Ps + (mt*16 + l15)*104 + ks2*32 + quad*8);
      f16x8 bb= *(const f16x8*)(Vt + (nt*16 + l15)*104 + ks2*32 + quad*8);
      acc = __builtin_amdgcn_mfma_f32_16x16x32_f16(a, bb, acc, 0, 0, 0);
    }
    #pragma unroll
    for (int r=0;r<4;r++){
      int row = mt*16 + quad*4 + r;
      if (row < 24)
        o[(qrow0 + row)*NDIM + hoff + nt*16 + l15] = f2h(acc[r]);
    }
  }
}

// ---------------------------------------------------------------------------
extern "C" void kernel_launch(void* const* d_in, const int* in_sizes, int n_in,
                              void* d_out, int out_size, void* d_ws, size_t ws_size,
                              hipStream_t stream)
{
  const float* x   = (const float*)d_in[0];
  const float* Wq  = (const float*)d_in[1];
  const float* bq  = (const float*)d_in[2];
  const float* Wk  = (const float*)d_in[3];
  const float* bk  = (const float*)d_in[4];
  const float* Wv  = (const float*)d_in[5];
  const float* bv  = (const float*)d_in[6];
  const float* Wo  = (const float*)d_in[7];
  const float* bo  = (const float*)d_in[8];
  const int*   pos = (const int*)d_in[9];

  u16* ws   = (u16*)d_ws;
  u16* WT   = ws;                               // 4 * 1M elems (8 MiB)
  u16* xb   = WT + 4u*1024u*1024u;              // 3072*1024 (6 MiB)
  u16* qkv  = xb + (size_t)MROWS*NDIM;          // 3 * 3072*1024 (18 MiB)
  u16* attn = WT;                               // overlay Wq/Wk/Wv^T slabs (6 MiB)
  float* outf = (float*)d_out;                  // fp32 [3072][1024]

  prep_kernel<<<dim3(1024 + MROWS*NDIM/(256*8)), 256, 0, stream>>>(
      x, Wq, Wk, Wv, Wo, WT, xb);
  gemm_bias_rope<64,64><<<dim3(16,48,3), 256, 0, stream>>>(
      xb, WT, bq, bk, bv, qkv, nullptr, pos, MROWS, /*rope_mats=*/2, /*f32_out=*/0);
  attn_kernel<<<dim3(64,16,2), 256, 0, stream>>>(
      qkv, qkv + (size_t)MROWS*NDIM, qkv + 2u*(size_t)MROWS*NDIM, attn);
  gemm_bias_rope<64,32><<<dim3(32,48,1), 256, 0, stream>>>(
      attn, WT + 3u*1024u*1024u, bo, bo, bo, nullptr, outf, pos, MROWS,
      /*rope_mats=*/0, /*f32_out=*/1);
}

// Round 11
// 171.314 us; speedup vs baseline: 1.2203x; 1.0243x over previous
//
#include <hip/hip_runtime.h>
#include <hip/hip_bf16.h>
#include <stdint.h>

typedef _Float16 f16;
typedef _Float16 f16x8 __attribute__((ext_vector_type(8)));
typedef float    f32x4 __attribute__((ext_vector_type(4)));
typedef unsigned short u16;
typedef unsigned int   u32;

#define S_LEN 1536
#define NDIM  1024
#define MROWS 3072

__device__ __forceinline__ u16 f2h(float f){           // fp32 -> f16 bits (RNE)
  _Float16 h = (_Float16)f;
  return __builtin_bit_cast(u16, h);
}
__device__ __forceinline__ float h2f(u16 u){
  return (float)__builtin_bit_cast(_Float16, u);
}

// async global->LDS, 16B per lane, LDS dest = wave-uniform base + lane*16
#define GLDS16(g, l) __builtin_amdgcn_global_load_lds( \
    (const __attribute__((address_space(1))) u32*)(const void*)(g), \
    (__attribute__((address_space(3))) u32*)(void*)(l), 16, 0, 0)

// ---------------------------------------------------------------------------
// Fused prep: blocks [0,1024) transpose the 4 weight matrices fp32->f16
// WT[n][k]; blocks [1024, 2560) cast x fp32->f16.
// ---------------------------------------------------------------------------
__global__ __launch_bounds__(256) void prep_kernel(
    const float* __restrict__ x,
    const float* __restrict__ w0, const float* __restrict__ w1,
    const float* __restrict__ w2, const float* __restrict__ w3,
    u16* __restrict__ wt_out, u16* __restrict__ xb_out)
{
  const int bid = blockIdx.x;
  const int t = threadIdx.x;
  if (bid >= 1024) {                       // ---- cast branch ----
    const int i = (bid - 1024) * 256 + t;  // elems [8i, 8i+8)
    const float4* p = (const float4*)x;
    float4 a = p[i*2], b = p[i*2+1];
    alignas(16) u16 tmp[8];
    tmp[0]=f2h(a.x); tmp[1]=f2h(a.y); tmp[2]=f2h(a.z); tmp[3]=f2h(a.w);
    tmp[4]=f2h(b.x); tmp[5]=f2h(b.y); tmp[6]=f2h(b.z); tmp[7]=f2h(b.w);
    *(uint4*)(xb_out + (size_t)i*8) = *(const uint4*)tmp;
    return;
  }
  // ---- transpose branch ----
  const int bx = bid & 15, by = (bid >> 4) & 15, bz = bid >> 8;
  const float* W = (bz==0)?w0:(bz==1)?w1:(bz==2)?w2:w3;
  u16* O = wt_out + (size_t)bz * (1024u*1024u);
  __shared__ __align__(16) u16 T[64*72];
  const int r0 = by*64, c0 = bx*64;
  #pragma unroll
  for (int i=0;i<2;i++){
    int v = t + i*256;
    int row = v >> 3, col = (v & 7) * 8;
    const float* src = W + (size_t)(r0+row)*NDIM + c0 + col;
    float4 a = *(const float4*)src;
    float4 b = *(const float4*)(src + 4);
    alignas(16) u16 tmp[8];
    tmp[0]=f2h(a.x); tmp[1]=f2h(a.y); tmp[2]=f2h(a.z); tmp[3]=f2h(a.w);
    tmp[4]=f2h(b.x); tmp[5]=f2h(b.y); tmp[6]=f2h(b.z); tmp[7]=f2h(b.w);
    *(uint4*)(T + row*72 + col) = *(const uint4*)tmp;
  }
  __syncthreads();
  #pragma unroll
  for (int i=0;i<2;i++){
    int v = t + i*256;
    int cc = v >> 3, rr = (v & 7) * 8;
    alignas(16) u16 tmp[8];
    #pragma unroll
    for (int j=0;j<8;j++) tmp[j] = T[(rr+j)*72 + cc];
    *(uint4*)(O + (size_t)(c0+cc)*NDIM + r0 + rr) = *(const uint4*)tmp;
  }
}

// ---------------------------------------------------------------------------
// C[M,1024] = A[M,1024] @ B + bias.  A f16, BT f16 (transposed).
// Proven single-buffer structure (R4/R7): tile TM x TN, BK=64 as two [.][32]
// subtiles via GLDS16, 2 barriers/iter. NEW (R11): XOR-swizzled LDS layout —
// 16B-group cg of local row r stored at group cg ^ (((r&15)>>1)&3). GLDS16
// can't pad, so the swizzle is applied by permuting the GLOBAL source column
// per lane (same 64B chunks touched -> coalescing unchanged) and XORing the
// fragment-read column. Kills the 8-way ds_read_b128 bank conflicts of the
// unpadded stride-64B layout (R10: 4.7M conflict-cycles/dispatch = ~7.7 us).
// History: dbuf (R5), B-direct (R8), BK=128 (R9), TN=32 out-proj (R10:
// doubles staged bytes) all neutral-or-worse. Staging wall ~20 B/cyc/CU.
// ---------------------------------------------------------------------------
#define SUBK 32

template<int TM, int TN>
__global__ __launch_bounds__(256) void gemm_bias_rope(
    const u16* __restrict__ A,     // [M][1024] f16
    const u16* __restrict__ BT,    // nmats x [1024][1024] f16 (transposed)
    const float* __restrict__ b0, const float* __restrict__ b1,
    const float* __restrict__ b2,
    u16*   __restrict__ Ch,        // f16 out (nmats slabs) or null
    float* __restrict__ Cf,        // fp32 out (z==0 only) or null
    const int* __restrict__ pos,
    int M, int rope_mats, int f32_out)
{
  constexpr int MI   = TM / 32;        // acc row-tiles per wave
  constexpr int NI   = TN / 32;        // acc col-tiles per wave
  constexpr int AW   = TM / 4;         // A rows staged per wave

  __shared__ __align__(16) u16 As[TM*64];   // 2 subtiles of [TM][32]
  __shared__ __align__(16) u16 Bs[TN*64];

  const int t    = threadIdx.x;
  const int lane = t & 63;
  const int wave = t >> 6;        // 0..3
  const int z    = blockIdx.z;
  const int m0   = blockIdx.y * TM;
  const int n0   = blockIdx.x * TN;
  const u16* Bm  = BT + (size_t)z * (1024u*1024u);
  u16*       Cm  = Ch ? (Ch + (size_t)z * ((size_t)M * NDIM)) : (u16*)0;
  const float* bias = (z==0) ? b0 : ((z==1) ? b1 : b2);

  const int wm   = (wave >> 1) * (TM/2);
  const int wn   = (wave & 1) * (TN/2);
  const int l15  = lane & 15;
  const int quad = lane >> 4;

  // staging lane map: one GLDS16 = 16 rows x 32 cols (64 lanes x 16B).
  // Swizzle: lane (lrow=lane>>2, cg=lane&3) sources global col group
  // cg ^ s where s = (lrow>>1)&3 = (lane>>3)&3.
  const int lrow = lane >> 2;
  const int lcol = (((lane & 3) ^ ((lane >> 3) & 3)) * 8);
  const u16* gA = A  + (size_t)(m0 + wave*AW + lrow)*NDIM + lcol;
  const u16* gB = Bm + (size_t)(n0 + (wave*16 % TN) + lrow)*NDIM + lcol;
  u16* lA = As + (wave*AW)*SUBK;   // wave-uniform LDS bases (subtile 0)
  u16* lB = Bs + ((wave*16 % TN))*SUBK;
  const bool bstage = (TN == 64) || (wave < TN/16);

  // fragment-read swizzle: row = (16-mult) + l15 -> s = (l15>>1)&3
  const int rsw = ((l15 >> 1) & 3);
  const int acol = ((quad ^ rsw) * 8);

  f32x4 acc[MI][NI];
  #pragma unroll
  for (int i=0;i<MI;i++)
    #pragma unroll
    for (int j=0;j<NI;j++)
      acc[i][j] = (f32x4){0.f,0.f,0.f,0.f};

  for (int k0 = 0; k0 < 1024; k0 += 64) {
    #pragma unroll
    for (int kb=0;kb<2;kb++){
      const u16* ga = gA + k0 + kb*SUBK;
      u16* lak = lA + kb*(TM*SUBK);
      GLDS16(ga, lak);
      if (TM == 128) GLDS16(ga + 16*NDIM, lak + 16*SUBK);
      if (bstage) GLDS16(gB + k0 + kb*SUBK, lB + kb*(TN*SUBK));
    }
    __syncthreads();                       // vmcnt(0) drain + barrier
    #pragma unroll
    for (int kb=0;kb<2;kb++){
      f16x8 af[MI], bfr[NI];
      #pragma unroll
      for (int i=0;i<MI;i++)
        af[i]  = *(const f16x8*)(As + kb*(TM*SUBK) + (wm + i*16 + l15)*SUBK + acol);
      #pragma unroll
      for (int j=0;j<NI;j++)
        bfr[j] = *(const f16x8*)(Bs + kb*(TN*SUBK) + (wn + j*16 + l15)*SUBK + acol);
      #pragma unroll
      for (int i=0;i<MI;i++)
        #pragma unroll
        for (int j=0;j<NI;j++)
          acc[i][j] = __builtin_amdgcn_mfma_f32_16x16x32_f16(
                          af[i], bfr[j], acc[i][j], 0, 0, 0);
    }
    __syncthreads();
  }

  // epilogue: bias (+ RoPE on cols 0..63 = head 0, tile n0==0) and store
  const bool rope_tile = (z < rope_mats) && (n0 == 0);
  #pragma unroll
  for (int i=0;i<MI;i++){
    const int rbase = m0 + wm + i*16 + quad*4;
    #pragma unroll
    for (int j=0;j<NI;j++){
      const int c  = n0 + wn + j*16 + l15;
      const float bv = bias[c];
      f32x4 v4 = acc[i][j];
      #pragma unroll
      for (int r=0;r<4;r++) v4[r] += bv;
      if (rope_tile) {
        const int   ii  = c >> 1;
        const float inv = powf(10000.0f, -(float)ii * (1.0f/32.0f));
        const float sgn = (c & 1) ? 1.0f : -1.0f;
        #pragma unroll
        for (int r=0;r<4;r++){
          float val     = v4[r];
          float partner = __shfl_xor(val, 1, 64);   // col c^1 lives in lane^1
          int   srow    = (rbase + r) % S_LEN;
          float ang     = (float)pos[srow] * inv;
          float sv, cv;
          sincosf(ang, &sv, &cv);
          v4[r] = val * cv + sgn * partner * sv;
        }
      }
      if (f32_out) {
        #pragma unroll
        for (int r=0;r<4;r++)
          Cf[(size_t)(rbase + r)*NDIM + c] = v4[r];
      } else {
        #pragma unroll
        for (int r=0;r<4;r++)
          Cm[(size_t)(rbase + r)*NDIM + c] = f2h(v4[r]);
      }
    }
  }
}

// ---------------------------------------------------------------------------
// Block-banded attention, MFMA version. R11: LDS diet 46.3 -> 34.6 KB
// (3 -> 4 blocks/CU): scores stored f16 (|s|<~1, safe) and P overlays the
// dead Qs/Ks region after the scores barrier. Layout (u16 elems):
//   [0,2304)      Qs  stride 72, 32 rows     (dead after scores)
//   [2304,8064)   Ks  stride 72, 80 rows     (dead after scores)
//   [0,3328)      Ps  stride 104, 32 rows    (overlay, after barrier)
//   [8064,14720)  Vt  stride 104, 64 rows
//   [14720,17280) Ss  stride 80, 32 rows, f16
// ---------------------------------------------------------------------------
__global__ __launch_bounds__(256) void attn_kernel(
    const u16* __restrict__ q, const u16* __restrict__ k,
    const u16* __restrict__ v, u16* __restrict__ o)
{
  const int qb = blockIdx.x;   // 0..63
  const int h  = blockIdx.y;   // 0..15
  const int b  = blockIdx.z;   // 0..1
  const int t  = threadIdx.x;
  const int lane = t & 63;
  const int wave = t >> 6;     // 0..3
  const int l15  = lane & 15;
  const int quad = lane >> 4;

  const int ks_ = (qb == 0) ? 0 : (qb - 1) * 24;
  const int ke_ = min(S_LEN, (qb + 2) * 24);
  const int kn  = ke_ - ks_;             // 48 or 72

  __shared__ __align__(16) u16 smem[17280];
  u16* Qs = smem;            // stride 72
  u16* Ks = smem + 2304;     // stride 72
  u16* Ps = smem;            // stride 104 (overlay)
  u16* Vt = smem + 8064;     // stride 104
  u16* Ss = smem + 14720;    // stride 80, f16

  const size_t qrow0 = (size_t)b*S_LEN + qb*24;
  const size_t krow0 = (size_t)b*S_LEN + ks_;
  const int hoff = h * 64;

  if (t < 192) {
    int row = t >> 3, col = (t & 7) * 8;
    *(uint4*)(Qs + row*72 + col) = *(const uint4*)(q + (qrow0+row)*NDIM + hoff + col);
  }
  for (int e = t; e < kn*8; e += 256) {
    int row = e >> 3, col = (e & 7) * 8;
    *(uint4*)(Ks + row*72 + col) = *(const uint4*)(k + (krow0+row)*NDIM + hoff + col);
    uint4 vv = *(const uint4*)(v + (krow0+row)*NDIM + hoff + col);
    const u16* pu = (const u16*)&vv;
    #pragma unroll
    for (int j=0;j<8;j++) Vt[(col+j)*104 + row] = pu[j];
  }
  for (int e = t; e < 64*48; e += 256) {
    int d = e / 48, c = 48 + (e - (e/48)*48);
    if (c >= kn) Vt[d*104 + c] = 0;
  }
  __syncthreads();

  const int ntn = (kn + 15) >> 4;
  for (int id = wave; id < 2*ntn; id += 4) {
    int mt = id / ntn, nt = id - (id/ntn)*ntn;
    f32x4 acc = (f32x4){0.f,0.f,0.f,0.f};
    #pragma unroll
    for (int ks2 = 0; ks2 < 2; ks2++) {
      f16x8 a = *(const f16x8*)(Qs + (mt*16 + l15)*72 + ks2*32 + quad*8);
      f16x8 bb= *(const f16x8*)(Ks + (nt*16 + l15)*72 + ks2*32 + quad*8);
      acc = __builtin_amdgcn_mfma_f32_16x16x32_f16(a, bb, acc, 0, 0, 0);
    }
    #pragma unroll
    for (int r=0;r<4;r++)
      Ss[(mt*16 + quad*4 + r)*80 + nt*16 + l15] = f2h(acc[r] * 0.125f);
  }
  __syncthreads();

  // softmax, 6 rows per wave; also writes Ps (overlaying dead Qs/Ks)
  #pragma unroll
  for (int i=0;i<6;i++){
    int row = wave*6 + i;
    float v0 = (lane      < kn) ? h2f(Ss[row*80 + lane])      : -1e30f;
    float v1 = (lane + 64 < kn) ? h2f(Ss[row*80 + 64 + lane]) : -1e30f;
    float m = fmaxf(v0, v1);
    #pragma unroll
    for (int off=32; off; off>>=1) m = fmaxf(m, __shfl_xor(m, off, 64));
    float p0 = __expf(v0 - m);
    float p1 = __expf(v1 - m);
    float s = p0 + p1;
    #pragma unroll
    for (int off=32; off; off>>=1) s += __shfl_xor(s, off, 64);
    float inv = 1.0f / s;
    Ps[row*104 + lane] = f2h(p0 * inv);
    if (lane < 32) Ps[row*104 + 64 + lane] = f2h(p1 * inv);
  }
  __syncthreads();

  const int kceil = (kn + 31) >> 5;
  #pragma unroll
  for (int id2 = 0; id2 < 2; id2++){
    int id = wave*2 + id2;
    int mt = id >> 2, nt = id & 3;
    f32x4 acc = (f32x4){0.f,0.f,0.f,0.f};
    for (int ks2 = 0; ks2 < kceil; ks2++) {
      f16x8 a = *(const f16x8*)(Ps + (mt*16 + l15)*104 + ks2*32 + quad*8);
      f16x8 bb= *(const f16x8*)(Vt + (nt*16 + l15)*104 + ks2*32 + quad*8);
      acc = __builtin_amdgcn_mfma_f32_16x16x32_f16(a, bb, acc, 0, 0, 0);
    }
    #pragma unroll
    for (int r=0;r<4;r++){
      int row = mt*16 + quad*4 + r;
      if (row < 24)
        o[(qrow0 + row)*NDIM + hoff + nt*16 + l15] = f2h(acc[r]);
    }
  }
}

// ---------------------------------------------------------------------------
extern "C" void kernel_launch(void* const* d_in, const int* in_sizes, int n_in,
                              void* d_out, int out_size, void* d_ws, size_t ws_size,
                              hipStream_t stream)
{
  const float* x   = (const float*)d_in[0];
  const float* Wq  = (const float*)d_in[1];
  const float* bq  = (const float*)d_in[2];
  const float* Wk  = (const float*)d_in[3];
  const float* bk  = (const float*)d_in[4];
  const float* Wv  = (const float*)d_in[5];
  const float* bv  = (const float*)d_in[6];
  const float* Wo  = (const float*)d_in[7];
  const float* bo  = (const float*)d_in[8];
  const int*   pos = (const int*)d_in[9];

  u16* ws   = (u16*)d_ws;
  u16* WT   = ws;                               // 4 * 1M elems (8 MiB)
  u16* xb   = WT + 4u*1024u*1024u;              // 3072*1024 (6 MiB)
  u16* qkv  = xb + (size_t)MROWS*NDIM;          // 3 * 3072*1024 (18 MiB)
  u16* attn = WT;                               // overlay Wq/Wk/Wv^T slabs (6 MiB)
  float* outf = (float*)d_out;                  // fp32 [3072][1024]

  prep_kernel<<<dim3(1024 + MROWS*NDIM/(256*8)), 256, 0, stream>>>(
      x, Wq, Wk, Wv, Wo, WT, xb);
  gemm_bias_rope<64,64><<<dim3(16,48,3), 256, 0, stream>>>(
      xb, WT, bq, bk, bv, qkv, nullptr, pos, MROWS, /*rope_mats=*/2, /*f32_out=*/0);
  attn_kernel<<<dim3(64,16,2), 256, 0, stream>>>(
      qkv, qkv + (size_t)MROWS*NDIM, qkv + 2u*(size_t)MROWS*NDIM, attn);
  gemm_bias_rope<64,64><<<dim3(16,48,1), 256, 0, stream>>>(
      attn, WT + 3u*1024u*1024u, bo, bo, bo, nullptr, outf, pos, MROWS,
      /*rope_mats=*/0, /*f32_out=*/1);
}